// Round 7
// baseline (1705.492 us; speedup 1.0000x reference)
//
#include <hip/hip_runtime.h>
#include <math.h>

#define BATCH   8
#define SEQ     512
#define IN_DIM  32
#define D_MODEL 512
#define N_LAYERS 4
#define D_INNER 1024
#define D_STATE 16
#define D_CONV  4
#define DT_RANK 32
#define NTOK    (BATCH * SEQ)   // 4096
#define CHUNK   128             // scan L-chunk staged in LDS

typedef __attribute__((ext_vector_type(8))) short short8_t;
typedef __attribute__((ext_vector_type(4))) float floatx4;

__device__ __forceinline__ float sigmoidf_(float x) { return 1.f / (1.f + __expf(-x)); }

// fp32 -> bf16 round-to-nearest-even (finite inputs)
__device__ __forceinline__ unsigned short f2bf(float f) {
    unsigned int u = __float_as_uint(f);
    return (unsigned short)((u + 0x7fffu + ((u >> 16) & 1u)) >> 16);
}
__device__ __forceinline__ float bf2f(unsigned short u) {
    return __uint_as_float((unsigned int)u << 16);
}

// sum x across each 16-lane row group via DPP (VALU pipe, no LDS traffic)
__device__ __forceinline__ float rowsum16(float x) {
    int t;
    t = __builtin_amdgcn_update_dpp(0, __float_as_int(x), 0xB1, 0xF, 0xF, true);  // quad_perm [1,0,3,2]
    x += __int_as_float(t);
    t = __builtin_amdgcn_update_dpp(0, __float_as_int(x), 0x4E, 0xF, 0xF, true);  // quad_perm [2,3,0,1]
    x += __int_as_float(t);
    t = __builtin_amdgcn_update_dpp(0, __float_as_int(x), 0x124, 0xF, 0xF, true); // row_ror:4
    x += __int_as_float(t);
    t = __builtin_amdgcn_update_dpp(0, __float_as_int(x), 0x128, 0xF, 0xF, true); // row_ror:8
    x += __int_as_float(t);
    return x;
}

// one-shot fp32->bf16 cast of the three MFMA weight tensors (single dispatch)
__global__ __launch_bounds__(256) void cast_all_kernel(
    const float* __restrict__ a, unsigned short* __restrict__ oa, int qa,   // vec4 counts
    const float* __restrict__ b, unsigned short* __restrict__ ob, int qb,
    const float* __restrict__ c, unsigned short* __restrict__ oc, int qc)
{
    int v = blockIdx.x * 256 + threadIdx.x;
    const float* in; unsigned short* out;
    if (v < qa)                { in = a; out = oa; }
    else if (v < qa + qb)      { v -= qa; in = b; out = ob; }
    else if (v < qa + qb + qc) { v -= qa + qb; in = c; out = oc; }
    else return;
    const float4 x = *(const float4*)&in[v * 4];
    ushort4 o;
    o.x = f2bf(x.x); o.y = f2bf(x.y); o.z = f2bf(x.z); o.w = f2bf(x.w);
    *(ushort4*)&out[v * 4] = o;
}

// ---------------- bf16 MFMA GEMM (in_proj / out_proj) ----------------
template<int BM, int BN>
__global__ __launch_bounds__(256) void gemm_mfma(
    const unsigned short* __restrict__ A, int lda,
    const unsigned short* __restrict__ W, int ldw,
    const float* __restrict__ R,
    float* __restrict__ C, int ldc,
    int K)
{
    constexpr int MT = BM / 32;
    constexpr int NT = BN / 32;
    constexpr int LDSP = 40;
    __shared__ __align__(16) unsigned short sA[BM * LDSP];
    __shared__ __align__(16) unsigned short sB[BN * LDSP];

    const int tid  = threadIdx.x;
    const int lane = tid & 63;
    const int wave = tid >> 6;
    const int wm0  = (wave >> 1) * (BM / 2);
    const int wn0  = (wave & 1) * (BN / 2);
    const int lrow = lane & 15;
    const int lko  = (lane >> 4) * 8;
    const int m0 = blockIdx.y * BM;
    const int n0 = blockIdx.x * BN;

    floatx4 acc[MT][NT];
    #pragma unroll
    for (int mt = 0; mt < MT; ++mt)
        #pragma unroll
        for (int nt = 0; nt < NT; ++nt)
            acc[mt][nt] = (floatx4){0.f, 0.f, 0.f, 0.f};

    for (int k0 = 0; k0 < K; k0 += 32) {
        #pragma unroll
        for (int it = 0; it < BM * 4 / 256; ++it) {
            const int idx = it * 256 + tid;
            const int r = idx >> 2, c = (idx & 3) * 8;
            *(short8_t*)&sA[r * LDSP + c] = *(const short8_t*)&A[(size_t)(m0 + r) * lda + k0 + c];
        }
        #pragma unroll
        for (int it = 0; it < BN * 4 / 256; ++it) {
            const int idx = it * 256 + tid;
            const int r = idx >> 2, c = (idx & 3) * 8;
            *(short8_t*)&sB[r * LDSP + c] = *(const short8_t*)&W[(size_t)(n0 + r) * ldw + k0 + c];
        }
        __syncthreads();
        short8_t af[MT], bfr[NT];
        #pragma unroll
        for (int mt = 0; mt < MT; ++mt)
            af[mt] = *(const short8_t*)&sA[(wm0 + mt * 16 + lrow) * LDSP + lko];
        #pragma unroll
        for (int nt = 0; nt < NT; ++nt)
            bfr[nt] = *(const short8_t*)&sB[(wn0 + nt * 16 + lrow) * LDSP + lko];
        #pragma unroll
        for (int mt = 0; mt < MT; ++mt)
            #pragma unroll
            for (int nt = 0; nt < NT; ++nt)
                acc[mt][nt] = __builtin_amdgcn_mfma_f32_16x16x32_bf16(af[mt], bfr[nt], acc[mt][nt], 0, 0, 0);
        __syncthreads();
    }

    #pragma unroll
    for (int mt = 0; mt < MT; ++mt) {
        const int mbase = m0 + wm0 + mt * 16 + (lane >> 4) * 4;
        #pragma unroll
        for (int nt = 0; nt < NT; ++nt) {
            const int n = n0 + wn0 + nt * 16 + (lane & 15);
            #pragma unroll
            for (int r = 0; r < 4; ++r) {
                float v = acc[mt][nt][r];
                if (R) v += R[(size_t)(mbase + r) * ldc + n];
                C[(size_t)(mbase + r) * ldc + n] = v;
            }
        }
    }
}

// ---------------- fused causal-dwconv + silu + x_proj MFMA ----------------
// A[m, k] = silu(conv(xz x-half)[m, k] + cb[k]) computed on the fly during staging
// (also written to xr_bf for the scan); dbc = A @ xpw.T  (N=64, K=1024).
// Grid: (1, NTOK/64). BM=BN=64, 4 waves 2x2.
__global__ __launch_bounds__(256) void conv_xproj_kernel(
    const float* __restrict__ xz, const float* __restrict__ cw,
    const float* __restrict__ cb,
    const unsigned short* __restrict__ Wbf,
    float* __restrict__ dbc, unsigned short* __restrict__ xr_bf)
{
    constexpr int LDSP = 40;
    __shared__ __align__(16) unsigned short sA[64 * LDSP];
    __shared__ __align__(16) unsigned short sB[64 * LDSP];

    const int tid  = threadIdx.x;
    const int lane = tid & 63;
    const int wave = tid >> 6;
    const int wm0  = (wave >> 1) * 32;
    const int wn0  = (wave & 1) * 32;
    const int lrow = lane & 15;
    const int lko  = (lane >> 4) * 8;
    const int m0   = blockIdx.y * 64;

    floatx4 acc[2][2];
    #pragma unroll
    for (int mt = 0; mt < 2; ++mt)
        #pragma unroll
        for (int nt = 0; nt < 2; ++nt)
            acc[mt][nt] = (floatx4){0.f, 0.f, 0.f, 0.f};

    for (int k0 = 0; k0 < D_INNER; k0 += 32) {
        // A staging: 64 x 32 conv+silu elements, 8 per thread
        #pragma unroll
        for (int it = 0; it < 8; ++it) {
            const int idx = it * 256 + tid;
            const int r = idx >> 5, c = idx & 31;
            const int tok = m0 + r;
            const int l   = tok & (SEQ - 1);
            const int col = k0 + c;
            float a = cb[col];
            #pragma unroll
            for (int k = 0; k < D_CONV; ++k) {
                const int t = l - (D_CONV - 1) + k;
                if (t >= 0)
                    a = fmaf(xz[(size_t)(tok + t - l) * (2 * D_INNER) + col], cw[col * D_CONV + k], a);
            }
            const float v = a * sigmoidf_(a);
            const unsigned short us = f2bf(v);
            sA[r * LDSP + c] = us;
            xr_bf[(size_t)tok * D_INNER + col] = us;
        }
        // B staging: 64 rows x 32 cols bf16, 1 ushort8 per thread
        {
            const int r = tid >> 2, cq = (tid & 3) * 8;
            *(short8_t*)&sB[r * LDSP + cq] = *(const short8_t*)&Wbf[(size_t)r * D_INNER + k0 + cq];
        }
        __syncthreads();
        short8_t af[2], bfr[2];
        #pragma unroll
        for (int mt = 0; mt < 2; ++mt)
            af[mt] = *(const short8_t*)&sA[(wm0 + mt * 16 + lrow) * LDSP + lko];
        #pragma unroll
        for (int nt = 0; nt < 2; ++nt)
            bfr[nt] = *(const short8_t*)&sB[(wn0 + nt * 16 + lrow) * LDSP + lko];
        #pragma unroll
        for (int mt = 0; mt < 2; ++mt)
            #pragma unroll
            for (int nt = 0; nt < 2; ++nt)
                acc[mt][nt] = __builtin_amdgcn_mfma_f32_16x16x32_bf16(af[mt], bfr[nt], acc[mt][nt], 0, 0, 0);
        __syncthreads();
    }

    #pragma unroll
    for (int mt = 0; mt < 2; ++mt) {
        const int mbase = m0 + wm0 + mt * 16 + (lane >> 4) * 4;
        #pragma unroll
        for (int nt = 0; nt < 2; ++nt) {
            const int n = wn0 + nt * 16 + (lane & 15);
            #pragma unroll
            for (int r = 0; r < 4; ++r)
                dbc[(size_t)(mbase + r) * 64 + n] = acc[mt][nt][r];
        }
    }
}

// ---------------- fp32 vector GEMM (encoder only) ----------------
__global__ __launch_bounds__(256) void gemm_bt64(
    const float* __restrict__ A, int lda,
    const float* __restrict__ W,
    const float* __restrict__ bias,
    float* __restrict__ C,
    int N, int K, int ldc)
{
    __shared__ __align__(16) float As[16][64];
    __shared__ __align__(16) float Ws[16][64];
    const int tid = threadIdx.x;
    const int tx = tid & 15, ty = tid >> 4;
    const int m0 = blockIdx.y * 64, n0 = blockIdx.x * 64;
    const int lm = tid >> 2;
    const int lk = (tid & 3) * 4;

    float acc[4][4] = {};
    for (int k0 = 0; k0 < K; k0 += 16) {
        float4 av = *(const float4*)&A[(size_t)(m0 + lm) * lda + k0 + lk];
        float4 wv = *(const float4*)&W[(size_t)(n0 + lm) * K   + k0 + lk];
        As[lk + 0][lm] = av.x; As[lk + 1][lm] = av.y; As[lk + 2][lm] = av.z; As[lk + 3][lm] = av.w;
        Ws[lk + 0][lm] = wv.x; Ws[lk + 1][lm] = wv.y; Ws[lk + 2][lm] = wv.z; Ws[lk + 3][lm] = wv.w;
        __syncthreads();
        #pragma unroll
        for (int k = 0; k < 16; ++k) {
            float4 a4 = *(const float4*)&As[k][ty * 4];
            float4 b4 = *(const float4*)&Ws[k][tx * 4];
            float a[4] = {a4.x, a4.y, a4.z, a4.w};
            float b[4] = {b4.x, b4.y, b4.z, b4.w};
            #pragma unroll
            for (int i = 0; i < 4; ++i)
                #pragma unroll
                for (int j = 0; j < 4; ++j)
                    acc[i][j] = fmaf(a[i], b[j], acc[i][j]);
        }
        __syncthreads();
    }
    #pragma unroll
    for (int i = 0; i < 4; ++i) {
        const int m = m0 + ty * 4 + i;
        #pragma unroll
        for (int j = 0; j < 4; ++j) {
            const int n = n0 + tx * 4 + j;
            C[(size_t)m * ldc + n] = acc[i][j] + bias[n];
        }
    }
}

// xn_bf[tok,:] = bf16( h[tok,:] * rsqrt(mean(h^2)+1e-5) * w )
__global__ __launch_bounds__(256) void rmsnorm_kernel(
    const float* __restrict__ h, const float* __restrict__ w, unsigned short* __restrict__ xn)
{
    const int tok = blockIdx.x, tid = threadIdx.x;
    const float* row = h + (size_t)tok * D_MODEL;
    float v0 = row[tid], v1 = row[tid + 256];
    float s = v0 * v0 + v1 * v1;
    #pragma unroll
    for (int off = 32; off > 0; off >>= 1) s += __shfl_down(s, off, 64);
    __shared__ float ss[4];
    if ((tid & 63) == 0) ss[tid >> 6] = s;
    __syncthreads();
    const float total = ss[0] + ss[1] + ss[2] + ss[3];
    const float scale = rsqrtf(total * (1.f / (float)D_MODEL) + 1e-5f);
    unsigned short* orow = xn + (size_t)tok * D_MODEL;
    orow[tid]       = f2bf(v0 * scale * w[tid]);
    orow[tid + 256] = f2bf(v1 * scale * w[tid + 256]);
}

// ---------------- fused dt_proj + selective scan + gate ----------------
// Thread = (d, n): n = tid & 15, dl = tid >> 4; grid = (D_INNER/16, BATCH).
// Per chunk: stage full dbc rows (dt 0:32 -> sDT, B/C 32:64 -> sBC) + x (bf16),
// compute delta = softplus(dt @ W_d + b_d) in fp32 (W_d in VGPRs), run recurrence,
// store y = (sum_n h C + D x) * silu(z_raw) as bf16.
__global__ __launch_bounds__(256) void scan_kernel(
    const float* __restrict__ dbc,   const unsigned short* __restrict__ xrbf,
    const float* __restrict__ xz,    const float* __restrict__ dtp_w,
    const float* __restrict__ dtp_b, const float* __restrict__ A_log,
    const float* __restrict__ Dp,    unsigned short* __restrict__ y)
{
    __shared__ __align__(16) float  sDT[CHUNK * 36];   // dt rows, padded 32->36
    __shared__ __align__(16) float2 sBC[CHUNK * 16];   // (B_n, C_n)
    __shared__ __align__(16) float2 sDX[CHUNK * 16];   // (.x=delta computed, .y=x)
    __shared__ __align__(16) float  sY [CHUNK * 16];
    const int b   = blockIdx.y;
    const int tid = threadIdx.x;
    const int n   = tid & 15;
    const int dl  = tid >> 4;
    const int d0  = blockIdx.x * 16;

    // per-thread dt_proj weight row (for delta compute phase: this thread's dl_c)
    const int dl_c = tid & 15;
    float4 wv[8];
    {
        const float* wr = dtp_w + (size_t)(d0 + dl_c) * DT_RANK;
        #pragma unroll
        for (int q = 0; q < 8; ++q) wv[q] = *(const float4*)&wr[q * 4];
    }
    const float dtb = dtp_b[d0 + dl_c];

    const float An = -__expf(A_log[(size_t)(d0 + dl) * D_STATE + n]);
    const float Dd = Dp[d0 + dl];

    float h = 0.f;
    for (int l0 = 0; l0 < SEQ; l0 += CHUNK) {
        // ---- stage dbc rows: 128 rows x 16 float4 = 8 per thread ----
        #pragma unroll
        for (int it = 0; it < 8; ++it) {
            const int idx = it * 256 + tid;
            const int row = idx >> 4, q = idx & 15;
            const float4 v = *(const float4*)&dbc[((size_t)(b * SEQ + l0 + row)) * 64 + q * 4];
            if (q < 8) {
                *(float4*)&sDT[row * 36 + q * 4] = v;
            } else if (q < 12) {
                const int c = (q - 8) * 4;
                float* base = (float*)&sBC[row * 16];
                base[2*(c+0)] = v.x; base[2*(c+1)] = v.y; base[2*(c+2)] = v.z; base[2*(c+3)] = v.w;
            } else {
                const int c = (q - 12) * 4;
                float* base = (float*)&sBC[row * 16];
                base[2*(c+0)+1] = v.x; base[2*(c+1)+1] = v.y; base[2*(c+2)+1] = v.z; base[2*(c+3)+1] = v.w;
            }
        }
        // ---- stage x (bf16 -> fp32 into sDX.y): 128 rows x 2 halves, 1 per thread ----
        {
            const int row = tid >> 1, half = tid & 1;
            const short8_t xv = *(const short8_t*)&xrbf[((size_t)(b * SEQ + l0 + row)) * D_INNER + d0 + half * 8];
            #pragma unroll
            for (int j = 0; j < 8; ++j)
                sDX[row * 16 + half * 8 + j].y = bf2f((unsigned short)xv[j]);
        }
        __syncthreads();

        // ---- delta compute: thread (dl_c, lg) does 8 l-values ----
        {
            const int lg = tid >> 4;
            #pragma unroll
            for (int ls = 0; ls < 8; ++ls) {
                const int l = lg * 8 + ls;
                float a = dtb;
                #pragma unroll
                for (int q = 0; q < 8; ++q) {
                    const float4 t4 = *(const float4*)&sDT[l * 36 + q * 4];
                    a = fmaf(t4.x, wv[q].x, a); a = fmaf(t4.y, wv[q].y, a);
                    a = fmaf(t4.z, wv[q].z, a); a = fmaf(t4.w, wv[q].w, a);
                }
                const float dlt = (a > 20.f) ? a : log1pf(__expf(a));
                sDX[l * 16 + dl_c].x = dlt;
            }
        }
        __syncthreads();

        // ---- recurrence ----
        #pragma unroll 4
        for (int l = 0; l < CHUNK; ++l) {
            const float2 dx = sDX[l * 16 + dl];
            const float2 bc = sBC[l * 16 + n];
            const float e = __expf(dx.x * An);
            h = fmaf(e, h, dx.x * dx.y * bc.x);
            const float p = rowsum16(h * bc.y);
            if (n == 0) sY[l * 16 + dl] = fmaf(Dd, dx.y, p);
        }
        __syncthreads();

        // ---- store: y = sY * silu(z_raw) ----
        #pragma unroll
        for (int it = 0; it < 2; ++it) {
            const int idx = it * 256 + tid;
            const int l = idx >> 2, q = idx & 3;
            const size_t row = (size_t)(b * SEQ + l0 + l);
            const float4 z4 = *(const float4*)&xz[row * 2 * D_INNER + D_INNER + d0 + q * 4];
            const float4 yv = *(const float4*)&sY[l * 16 + q * 4];
            ushort4 o;
            o.x = f2bf(yv.x * z4.x * sigmoidf_(z4.x));
            o.y = f2bf(yv.y * z4.y * sigmoidf_(z4.y));
            o.z = f2bf(yv.z * z4.z * sigmoidf_(z4.z));
            o.w = f2bf(yv.w * z4.w * sigmoidf_(z4.w));
            *(ushort4*)&y[row * D_INNER + d0 + q * 4] = o;
        }
        // next chunk's first __syncthreads orders sY reads before overwrite phases
    }
}

// fused decoder: out[b] = relu(h_last @ w1.T + b1) @ w2 + b2; one block per batch
__global__ __launch_bounds__(256) void dec_kernel(
    const float* __restrict__ h, const float* __restrict__ w1, const float* __restrict__ b1,
    const float* __restrict__ w2, const float* __restrict__ b2, float* __restrict__ out)
{
    __shared__ __align__(16) float hr[D_MODEL];
    __shared__ float part[4];
    const int b = blockIdx.x, j = threadIdx.x;
    const float* row = h + ((size_t)(b * SEQ + SEQ - 1)) * D_MODEL;
    hr[j] = row[j];
    hr[j + 256] = row[j + 256];
    __syncthreads();
    float acc = b1[j];
    const float* wr = w1 + (size_t)j * D_MODEL;
    for (int k = 0; k < D_MODEL; k += 4) {
        const float4 wvv = *(const float4*)&wr[k];
        const float4 hv = *(const float4*)&hr[k];
        acc = fmaf(wvv.x, hv.x, acc); acc = fmaf(wvv.y, hv.y, acc);
        acc = fmaf(wvv.z, hv.z, acc); acc = fmaf(wvv.w, hv.w, acc);
    }
    float s = fmaxf(acc, 0.f) * w2[j];
    #pragma unroll
    for (int off = 32; off > 0; off >>= 1) s += __shfl_down(s, off, 64);
    if ((j & 63) == 0) part[j >> 6] = s;
    __syncthreads();
    if (j == 0) out[b] = part[0] + part[1] + part[2] + part[3] + b2[0];
}

extern "C" void kernel_launch(void* const* d_in, const int* in_sizes, int n_in,
                              void* d_out, int out_size, void* d_ws, size_t ws_size,
                              hipStream_t stream)
{
    const float* x      = (const float*)d_in[0];
    const float* enc_w  = (const float*)d_in[1];
    const float* enc_b  = (const float*)d_in[2];
    const float* in_w   = (const float*)d_in[3];
    const float* conv_w = (const float*)d_in[4];
    const float* conv_b = (const float*)d_in[5];
    const float* xp_w   = (const float*)d_in[6];
    const float* dtp_w  = (const float*)d_in[7];
    const float* dtp_b  = (const float*)d_in[8];
    const float* A_log  = (const float*)d_in[9];
    const float* Dp     = (const float*)d_in[10];
    const float* out_w  = (const float*)d_in[11];
    const float* norm_w = (const float*)d_in[12];
    const float* dec_w1 = (const float*)d_in[13];
    const float* dec_b1 = (const float*)d_in[14];
    const float* dec_w2 = (const float*)d_in[15];
    const float* dec_b2 = (const float*)d_in[16];
    float* out = (float*)d_out;

    // workspace layout
    float* ws    = (float*)d_ws;
    float* h     = ws;                                   // NTOK*512
    float* xz    = h     + (size_t)NTOK * D_MODEL;       // NTOK*2048
    float* dbc   = xz    + (size_t)NTOK * 2 * D_INNER;   // NTOK*64
    unsigned short* xn_bf   = (unsigned short*)(dbc + (size_t)NTOK * 64);            // NTOK*512
    unsigned short* y_bf    = xn_bf   + (size_t)NTOK * D_MODEL;                      // NTOK*1024
    unsigned short* xr_bf   = y_bf    + (size_t)NTOK * D_INNER;                      // NTOK*1024
    unsigned short* inw_bf  = xr_bf   + (size_t)NTOK * D_INNER;                      // 4*2048*512
    unsigned short* outw_bf = inw_bf  + (size_t)N_LAYERS * 2 * D_INNER * D_MODEL;    // 4*512*1024
    unsigned short* xpw_bf  = outw_bf + (size_t)N_LAYERS * D_MODEL * D_INNER;        // 4*64*1024

    const int qa = N_LAYERS * 2 * D_INNER * D_MODEL / 4;   // in_proj  vec4 count
    const int qb = N_LAYERS * D_MODEL * D_INNER / 4;       // out_proj
    const int qc = N_LAYERS * 64 * D_INNER / 4;            // x_proj
    cast_all_kernel<<<(qa + qb + qc + 255) / 256, 256, 0, stream>>>(
        in_w, inw_bf, qa, out_w, outw_bf, qb, xp_w, xpw_bf, qc);

    // encoder: h = x @ enc_w.T + enc_b   (fp32, K=32)
    gemm_bt64<<<dim3(D_MODEL / 64, NTOK / 64), 256, 0, stream>>>(
        x, IN_DIM, enc_w, enc_b, h, D_MODEL, IN_DIM, D_MODEL);

    for (int i = 0; i < N_LAYERS; ++i) {
        rmsnorm_kernel<<<NTOK, 256, 0, stream>>>(h, norm_w + (size_t)i * D_MODEL, xn_bf);

        // xz = xn @ in_proj_w[i].T   (4096 x 2048, K=512)  [bf16 MFMA]
        gemm_mfma<128, 128><<<dim3(2 * D_INNER / 128, NTOK / 128), 256, 0, stream>>>(
            xn_bf, D_MODEL, inw_bf + (size_t)i * 2 * D_INNER * D_MODEL, D_MODEL,
            nullptr, xz, 2 * D_INNER, D_MODEL);

        // fused conv+silu (-> xr_bf) + x_proj MFMA (-> dbc fp32)
        conv_xproj_kernel<<<dim3(1, NTOK / 64), 256, 0, stream>>>(
            xz, conv_w + (size_t)i * D_INNER * D_CONV, conv_b + (size_t)i * D_INNER,
            xpw_bf + (size_t)i * 64 * D_INNER, dbc, xr_bf);

        // fused dt_proj + scan + D skip + silu(z) gate; y -> bf16
        scan_kernel<<<dim3(D_INNER / 16, BATCH), 256, 0, stream>>>(
            dbc, xr_bf, xz,
            dtp_w + (size_t)i * D_INNER * DT_RANK, dtp_b + (size_t)i * D_INNER,
            A_log + (size_t)i * D_INNER * D_STATE, Dp + (size_t)i * D_INNER, y_bf);

        // h = h + y @ out_proj_w[i].T   (4096 x 512, K=1024)  [bf16 MFMA]
        gemm_mfma<128, 64><<<dim3(D_MODEL / 64, NTOK / 128), 256, 0, stream>>>(
            y_bf, D_INNER, outw_bf + (size_t)i * D_MODEL * D_INNER, D_INNER,
            h, h, D_MODEL, D_INNER);
    }

    dec_kernel<<<BATCH, 256, 0, stream>>>(h, dec_w1, dec_b1, dec_w2, dec_b2, out);
}

// Round 8
// 808.914 us; speedup vs baseline: 2.1084x; 2.1084x over previous
//
#include <hip/hip_runtime.h>
#include <math.h>

#define BATCH   8
#define SEQ     512
#define IN_DIM  32
#define D_MODEL 512
#define N_LAYERS 4
#define D_INNER 1024
#define D_STATE 16
#define D_CONV  4
#define DT_RANK 32
#define NTOK    (BATCH * SEQ)   // 4096
#define CHUNK   128             // scan L-chunk staged in LDS

typedef __attribute__((ext_vector_type(8))) short short8_t;
typedef __attribute__((ext_vector_type(4))) float floatx4;

__device__ __forceinline__ float sigmoidf_(float x) { return 1.f / (1.f + __expf(-x)); }

// fp32 -> bf16 round-to-nearest-even (finite inputs)
__device__ __forceinline__ unsigned short f2bf(float f) {
    unsigned int u = __float_as_uint(f);
    return (unsigned short)((u + 0x7fffu + ((u >> 16) & 1u)) >> 16);
}
__device__ __forceinline__ float bf2f(unsigned short u) {
    return __uint_as_float((unsigned int)u << 16);
}

// sum x across each 16-lane row group via DPP (VALU pipe, no LDS traffic)
__device__ __forceinline__ float rowsum16(float x) {
    int t;
    t = __builtin_amdgcn_update_dpp(0, __float_as_int(x), 0xB1, 0xF, 0xF, true);  // quad_perm [1,0,3,2]
    x += __int_as_float(t);
    t = __builtin_amdgcn_update_dpp(0, __float_as_int(x), 0x4E, 0xF, 0xF, true);  // quad_perm [2,3,0,1]
    x += __int_as_float(t);
    t = __builtin_amdgcn_update_dpp(0, __float_as_int(x), 0x124, 0xF, 0xF, true); // row_ror:4
    x += __int_as_float(t);
    t = __builtin_amdgcn_update_dpp(0, __float_as_int(x), 0x128, 0xF, 0xF, true); // row_ror:8
    x += __int_as_float(t);
    return x;
}

// one-shot fp32->bf16 cast of the three MFMA weight tensors (single dispatch)
__global__ __launch_bounds__(256) void cast_all_kernel(
    const float* __restrict__ a, unsigned short* __restrict__ oa, int qa,   // vec4 counts
    const float* __restrict__ b, unsigned short* __restrict__ ob, int qb,
    const float* __restrict__ c, unsigned short* __restrict__ oc, int qc)
{
    int v = blockIdx.x * 256 + threadIdx.x;
    const float* in; unsigned short* out;
    if (v < qa)                { in = a; out = oa; }
    else if (v < qa + qb)      { v -= qa; in = b; out = ob; }
    else if (v < qa + qb + qc) { v -= qa + qb; in = c; out = oc; }
    else return;
    const float4 x = *(const float4*)&in[v * 4];
    ushort4 o;
    o.x = f2bf(x.x); o.y = f2bf(x.y); o.z = f2bf(x.z); o.w = f2bf(x.w);
    *(ushort4*)&out[v * 4] = o;
}

// ---------------- bf16 MFMA GEMM ----------------
// C[m,n] = dot(A[m,0:K], W[n,0:K]) (+ R[m,n]); A,W bf16, C/R fp32.
// Block tile BM x BN, 4 waves 2x2, BK=32. LDS rows padded to 40 bf16 -> 2-way conflicts only.
template<int BM, int BN>
__global__ __launch_bounds__(256) void gemm_mfma(
    const unsigned short* __restrict__ A, int lda,
    const unsigned short* __restrict__ W, int ldw,
    const float* __restrict__ R,
    float* __restrict__ C, int ldc,
    int K)
{
    constexpr int MT = BM / 32;
    constexpr int NT = BN / 32;
    constexpr int LDSP = 40;
    __shared__ __align__(16) unsigned short sA[BM * LDSP];
    __shared__ __align__(16) unsigned short sB[BN * LDSP];

    const int tid  = threadIdx.x;
    const int lane = tid & 63;
    const int wave = tid >> 6;
    const int wm0  = (wave >> 1) * (BM / 2);
    const int wn0  = (wave & 1) * (BN / 2);
    const int lrow = lane & 15;
    const int lko  = (lane >> 4) * 8;
    const int m0 = blockIdx.y * BM;
    const int n0 = blockIdx.x * BN;

    floatx4 acc[MT][NT];
    #pragma unroll
    for (int mt = 0; mt < MT; ++mt)
        #pragma unroll
        for (int nt = 0; nt < NT; ++nt)
            acc[mt][nt] = (floatx4){0.f, 0.f, 0.f, 0.f};

    for (int k0 = 0; k0 < K; k0 += 32) {
        #pragma unroll
        for (int it = 0; it < BM * 4 / 256; ++it) {
            const int idx = it * 256 + tid;
            const int r = idx >> 2, c = (idx & 3) * 8;
            *(short8_t*)&sA[r * LDSP + c] = *(const short8_t*)&A[(size_t)(m0 + r) * lda + k0 + c];
        }
        #pragma unroll
        for (int it = 0; it < BN * 4 / 256; ++it) {
            const int idx = it * 256 + tid;
            const int r = idx >> 2, c = (idx & 3) * 8;
            *(short8_t*)&sB[r * LDSP + c] = *(const short8_t*)&W[(size_t)(n0 + r) * ldw + k0 + c];
        }
        __syncthreads();
        short8_t af[MT], bfr[NT];
        #pragma unroll
        for (int mt = 0; mt < MT; ++mt)
            af[mt] = *(const short8_t*)&sA[(wm0 + mt * 16 + lrow) * LDSP + lko];
        #pragma unroll
        for (int nt = 0; nt < NT; ++nt)
            bfr[nt] = *(const short8_t*)&sB[(wn0 + nt * 16 + lrow) * LDSP + lko];
        #pragma unroll
        for (int mt = 0; mt < MT; ++mt)
            #pragma unroll
            for (int nt = 0; nt < NT; ++nt)
                acc[mt][nt] = __builtin_amdgcn_mfma_f32_16x16x32_bf16(af[mt], bfr[nt], acc[mt][nt], 0, 0, 0);
        __syncthreads();
    }

    #pragma unroll
    for (int mt = 0; mt < MT; ++mt) {
        const int mbase = m0 + wm0 + mt * 16 + (lane >> 4) * 4;
        #pragma unroll
        for (int nt = 0; nt < NT; ++nt) {
            const int n = n0 + wn0 + nt * 16 + (lane & 15);
            #pragma unroll
            for (int r = 0; r < 4; ++r) {
                float v = acc[mt][nt][r];
                if (R) v += R[(size_t)(mbase + r) * ldc + n];
                C[(size_t)(mbase + r) * ldc + n] = v;
            }
        }
    }
}

// ---------------- fp32 vector GEMM (encoder only) ----------------
__global__ __launch_bounds__(256) void gemm_bt64(
    const float* __restrict__ A, int lda,
    const float* __restrict__ W,
    const float* __restrict__ bias,
    float* __restrict__ C,
    int N, int K, int ldc)
{
    __shared__ __align__(16) float As[16][64];
    __shared__ __align__(16) float Ws[16][64];
    const int tid = threadIdx.x;
    const int tx = tid & 15, ty = tid >> 4;
    const int m0 = blockIdx.y * 64, n0 = blockIdx.x * 64;
    const int lm = tid >> 2;
    const int lk = (tid & 3) * 4;

    float acc[4][4] = {};
    for (int k0 = 0; k0 < K; k0 += 16) {
        float4 av = *(const float4*)&A[(size_t)(m0 + lm) * lda + k0 + lk];
        float4 wv = *(const float4*)&W[(size_t)(n0 + lm) * K   + k0 + lk];
        As[lk + 0][lm] = av.x; As[lk + 1][lm] = av.y; As[lk + 2][lm] = av.z; As[lk + 3][lm] = av.w;
        Ws[lk + 0][lm] = wv.x; Ws[lk + 1][lm] = wv.y; Ws[lk + 2][lm] = wv.z; Ws[lk + 3][lm] = wv.w;
        __syncthreads();
        #pragma unroll
        for (int k = 0; k < 16; ++k) {
            float4 a4 = *(const float4*)&As[k][ty * 4];
            float4 b4 = *(const float4*)&Ws[k][tx * 4];
            float a[4] = {a4.x, a4.y, a4.z, a4.w};
            float b[4] = {b4.x, b4.y, b4.z, b4.w};
            #pragma unroll
            for (int i = 0; i < 4; ++i)
                #pragma unroll
                for (int j = 0; j < 4; ++j)
                    acc[i][j] = fmaf(a[i], b[j], acc[i][j]);
        }
        __syncthreads();
    }
    #pragma unroll
    for (int i = 0; i < 4; ++i) {
        const int m = m0 + ty * 4 + i;
        #pragma unroll
        for (int j = 0; j < 4; ++j) {
            const int n = n0 + tx * 4 + j;
            C[(size_t)m * ldc + n] = acc[i][j] + bias[n];
        }
    }
}

// xn_bf[tok,:] = bf16( h[tok,:] * rsqrt(mean(h^2)+1e-5) * w )
__global__ __launch_bounds__(256) void rmsnorm_kernel(
    const float* __restrict__ h, const float* __restrict__ w, unsigned short* __restrict__ xn)
{
    const int tok = blockIdx.x, tid = threadIdx.x;
    const float* row = h + (size_t)tok * D_MODEL;
    float v0 = row[tid], v1 = row[tid + 256];
    float s = v0 * v0 + v1 * v1;
    #pragma unroll
    for (int off = 32; off > 0; off >>= 1) s += __shfl_down(s, off, 64);
    __shared__ float ss[4];
    if ((tid & 63) == 0) ss[tid >> 6] = s;
    __syncthreads();
    const float total = ss[0] + ss[1] + ss[2] + ss[3];
    const float scale = rsqrtf(total * (1.f / (float)D_MODEL) + 1e-5f);
    unsigned short* orow = xn + (size_t)tok * D_MODEL;
    orow[tid]       = f2bf(v0 * scale * w[tid]);
    orow[tid + 256] = f2bf(v1 * scale * w[tid + 256]);
}

// causal dwconv + silu over xz x-half -> xr_bf (bf16). 16384 blocks, fully coalesced.
__global__ __launch_bounds__(256) void conv_silu_kernel(
    const float* __restrict__ xz, const float* __restrict__ cw,
    const float* __restrict__ cb, unsigned short* __restrict__ xr_bf)
{
    const int idx = blockIdx.x * 256 + threadIdx.x;   // over NTOK*D_INNER
    const int d   = idx & (D_INNER - 1);
    const int tok = idx >> 10;
    const int l   = tok & (SEQ - 1);
    float acc = cb[d];
    #pragma unroll
    for (int k = 0; k < D_CONV; ++k) {
        const int t = l - (D_CONV - 1) + k;
        if (t >= 0)
            acc = fmaf(xz[(size_t)(tok + t - l) * (2 * D_INNER) + d], cw[d * D_CONV + k], acc);
    }
    const float v = acc * sigmoidf_(acc);
    xr_bf[(size_t)tok * D_INNER + d] = f2bf(v);
}

// ---------------- fused dt_proj + selective scan + gate ----------------
// Thread = (d, n): n = tid & 15, dl = tid >> 4; grid = (D_INNER/16, BATCH).
// Per chunk: stage full dbc rows (dt 0:32 -> sDT, B/C 32:64 -> sBC) + x (bf16),
// compute delta = softplus(dt @ W_d + b_d) in fp32 (W_d in VGPRs), run recurrence,
// store y = (sum_n h C + D x) * silu(z_raw) as bf16.
__global__ __launch_bounds__(256) void scan_kernel(
    const float* __restrict__ dbc,   const unsigned short* __restrict__ xrbf,
    const float* __restrict__ xz,    const float* __restrict__ dtp_w,
    const float* __restrict__ dtp_b, const float* __restrict__ A_log,
    const float* __restrict__ Dp,    unsigned short* __restrict__ y)
{
    __shared__ __align__(16) float  sDT[CHUNK * 36];   // dt rows, padded 32->36
    __shared__ __align__(16) float2 sBC[CHUNK * 16];   // (B_n, C_n)
    __shared__ __align__(16) float2 sDX[CHUNK * 16];   // (.x=delta computed, .y=x)
    __shared__ __align__(16) float  sY [CHUNK * 16];
    const int b   = blockIdx.y;
    const int tid = threadIdx.x;
    const int n   = tid & 15;
    const int dl  = tid >> 4;
    const int d0  = blockIdx.x * 16;

    // per-thread dt_proj weight row (for delta compute phase: this thread's dl_c)
    const int dl_c = tid & 15;
    float4 wv[8];
    {
        const float* wr = dtp_w + (size_t)(d0 + dl_c) * DT_RANK;
        #pragma unroll
        for (int q = 0; q < 8; ++q) wv[q] = *(const float4*)&wr[q * 4];
    }
    const float dtb = dtp_b[d0 + dl_c];

    const float An = -__expf(A_log[(size_t)(d0 + dl) * D_STATE + n]);
    const float Dd = Dp[d0 + dl];

    float h = 0.f;
    for (int l0 = 0; l0 < SEQ; l0 += CHUNK) {
        // ---- stage dbc rows: 128 rows x 16 float4 = 8 per thread ----
        #pragma unroll
        for (int it = 0; it < 8; ++it) {
            const int idx = it * 256 + tid;
            const int row = idx >> 4, q = idx & 15;
            const float4 v = *(const float4*)&dbc[((size_t)(b * SEQ + l0 + row)) * 64 + q * 4];
            if (q < 8) {
                *(float4*)&sDT[row * 36 + q * 4] = v;
            } else if (q < 12) {
                const int c = (q - 8) * 4;
                float* base = (float*)&sBC[row * 16];
                base[2*(c+0)] = v.x; base[2*(c+1)] = v.y; base[2*(c+2)] = v.z; base[2*(c+3)] = v.w;
            } else {
                const int c = (q - 12) * 4;
                float* base = (float*)&sBC[row * 16];
                base[2*(c+0)+1] = v.x; base[2*(c+1)+1] = v.y; base[2*(c+2)+1] = v.z; base[2*(c+3)+1] = v.w;
            }
        }
        // ---- stage x (bf16 -> fp32 into sDX.y): 128 rows x 2 halves, 1 per thread ----
        {
            const int row = tid >> 1, half = tid & 1;
            const short8_t xv = *(const short8_t*)&xrbf[((size_t)(b * SEQ + l0 + row)) * D_INNER + d0 + half * 8];
            #pragma unroll
            for (int j = 0; j < 8; ++j)
                sDX[row * 16 + half * 8 + j].y = bf2f((unsigned short)xv[j]);
        }
        __syncthreads();

        // ---- delta compute: thread (dl_c, lg) does 8 l-values ----
        {
            const int lg = tid >> 4;
            #pragma unroll
            for (int ls = 0; ls < 8; ++ls) {
                const int l = lg * 8 + ls;
                float a = dtb;
                #pragma unroll
                for (int q = 0; q < 8; ++q) {
                    const float4 t4 = *(const float4*)&sDT[l * 36 + q * 4];
                    a = fmaf(t4.x, wv[q].x, a); a = fmaf(t4.y, wv[q].y, a);
                    a = fmaf(t4.z, wv[q].z, a); a = fmaf(t4.w, wv[q].w, a);
                }
                const float dlt = (a > 20.f) ? a : log1pf(__expf(a));
                sDX[l * 16 + dl_c].x = dlt;
            }
        }
        __syncthreads();

        // ---- recurrence ----
        #pragma unroll 4
        for (int l = 0; l < CHUNK; ++l) {
            const float2 dx = sDX[l * 16 + dl];
            const float2 bc = sBC[l * 16 + n];
            const float e = __expf(dx.x * An);
            h = fmaf(e, h, dx.x * dx.y * bc.x);
            const float p = rowsum16(h * bc.y);
            if (n == 0) sY[l * 16 + dl] = fmaf(Dd, dx.y, p);
        }
        __syncthreads();

        // ---- store: y = sY * silu(z_raw) ----
        #pragma unroll
        for (int it = 0; it < 2; ++it) {
            const int idx = it * 256 + tid;
            const int l = idx >> 2, q = idx & 3;
            const size_t row = (size_t)(b * SEQ + l0 + l);
            const float4 z4 = *(const float4*)&xz[row * 2 * D_INNER + D_INNER + d0 + q * 4];
            const float4 yv = *(const float4*)&sY[l * 16 + q * 4];
            ushort4 o;
            o.x = f2bf(yv.x * z4.x * sigmoidf_(z4.x));
            o.y = f2bf(yv.y * z4.y * sigmoidf_(z4.y));
            o.z = f2bf(yv.z * z4.z * sigmoidf_(z4.z));
            o.w = f2bf(yv.w * z4.w * sigmoidf_(z4.w));
            *(ushort4*)&y[row * D_INNER + d0 + q * 4] = o;
        }
        // next chunk's first __syncthreads orders sY reads before overwrite phases
    }
}

// fused decoder: out[b] = relu(h_last @ w1.T + b1) @ w2 + b2; one block per batch
__global__ __launch_bounds__(256) void dec_kernel(
    const float* __restrict__ h, const float* __restrict__ w1, const float* __restrict__ b1,
    const float* __restrict__ w2, const float* __restrict__ b2, float* __restrict__ out)
{
    __shared__ __align__(16) float hr[D_MODEL];
    __shared__ float part[4];
    const int b = blockIdx.x, j = threadIdx.x;
    const float* row = h + ((size_t)(b * SEQ + SEQ - 1)) * D_MODEL;
    hr[j] = row[j];
    hr[j + 256] = row[j + 256];
    __syncthreads();
    float acc = b1[j];
    const float* wr = w1 + (size_t)j * D_MODEL;
    for (int k = 0; k < D_MODEL; k += 4) {
        const float4 wvv = *(const float4*)&wr[k];
        const float4 hv = *(const float4*)&hr[k];
        acc = fmaf(wvv.x, hv.x, acc); acc = fmaf(wvv.y, hv.y, acc);
        acc = fmaf(wvv.z, hv.z, acc); acc = fmaf(wvv.w, hv.w, acc);
    }
    float s = fmaxf(acc, 0.f) * w2[j];
    #pragma unroll
    for (int off = 32; off > 0; off >>= 1) s += __shfl_down(s, off, 64);
    if ((j & 63) == 0) part[j >> 6] = s;
    __syncthreads();
    if (j == 0) out[b] = part[0] + part[1] + part[2] + part[3] + b2[0];
}

extern "C" void kernel_launch(void* const* d_in, const int* in_sizes, int n_in,
                              void* d_out, int out_size, void* d_ws, size_t ws_size,
                              hipStream_t stream)
{
    const float* x      = (const float*)d_in[0];
    const float* enc_w  = (const float*)d_in[1];
    const float* enc_b  = (const float*)d_in[2];
    const float* in_w   = (const float*)d_in[3];
    const float* conv_w = (const float*)d_in[4];
    const float* conv_b = (const float*)d_in[5];
    const float* xp_w   = (const float*)d_in[6];
    const float* dtp_w  = (const float*)d_in[7];
    const float* dtp_b  = (const float*)d_in[8];
    const float* A_log  = (const float*)d_in[9];
    const float* Dp     = (const float*)d_in[10];
    const float* out_w  = (const float*)d_in[11];
    const float* norm_w = (const float*)d_in[12];
    const float* dec_w1 = (const float*)d_in[13];
    const float* dec_b1 = (const float*)d_in[14];
    const float* dec_w2 = (const float*)d_in[15];
    const float* dec_b2 = (const float*)d_in[16];
    float* out = (float*)d_out;

    // workspace layout
    float* ws    = (float*)d_ws;
    float* h     = ws;                                   // NTOK*512
    float* xz    = h     + (size_t)NTOK * D_MODEL;       // NTOK*2048
    float* dbc   = xz    + (size_t)NTOK * 2 * D_INNER;   // NTOK*64
    unsigned short* xn_bf   = (unsigned short*)(dbc + (size_t)NTOK * 64);            // NTOK*512
    unsigned short* y_bf    = xn_bf   + (size_t)NTOK * D_MODEL;                      // NTOK*1024
    unsigned short* xr_bf   = y_bf    + (size_t)NTOK * D_INNER;                      // NTOK*1024
    unsigned short* inw_bf  = xr_bf   + (size_t)NTOK * D_INNER;                      // 4*2048*512
    unsigned short* outw_bf = inw_bf  + (size_t)N_LAYERS * 2 * D_INNER * D_MODEL;    // 4*512*1024
    unsigned short* xpw_bf  = outw_bf + (size_t)N_LAYERS * D_MODEL * D_INNER;        // 4*64*1024

    const int qa = N_LAYERS * 2 * D_INNER * D_MODEL / 4;   // in_proj  vec4 count
    const int qb = N_LAYERS * D_MODEL * D_INNER / 4;       // out_proj
    const int qc = N_LAYERS * 64 * D_INNER / 4;            // x_proj
    cast_all_kernel<<<(qa + qb + qc + 255) / 256, 256, 0, stream>>>(
        in_w, inw_bf, qa, out_w, outw_bf, qb, xp_w, xpw_bf, qc);

    // encoder: h = x @ enc_w.T + enc_b   (fp32, K=32)
    gemm_bt64<<<dim3(D_MODEL / 64, NTOK / 64), 256, 0, stream>>>(
        x, IN_DIM, enc_w, enc_b, h, D_MODEL, IN_DIM, D_MODEL);

    for (int i = 0; i < N_LAYERS; ++i) {
        rmsnorm_kernel<<<NTOK, 256, 0, stream>>>(h, norm_w + (size_t)i * D_MODEL, xn_bf);

        // xz = xn @ in_proj_w[i].T   (4096 x 2048, K=512)  [bf16 MFMA]
        gemm_mfma<128, 128><<<dim3(2 * D_INNER / 128, NTOK / 128), 256, 0, stream>>>(
            xn_bf, D_MODEL, inw_bf + (size_t)i * 2 * D_INNER * D_MODEL, D_MODEL,
            nullptr, xz, 2 * D_INNER, D_MODEL);

        // xr_bf = bf16(silu(causal_dwconv(xz x-half) + cb))   [wide elementwise]
        conv_silu_kernel<<<NTOK * D_INNER / 256, 256, 0, stream>>>(
            xz, conv_w + (size_t)i * D_INNER * D_CONV, conv_b + (size_t)i * D_INNER, xr_bf);

        // dbc = xr @ x_proj_w[i].T   (4096 x 64, K=1024)  [bf16 MFMA]
        gemm_mfma<64, 64><<<dim3(1, NTOK / 64), 256, 0, stream>>>(
            xr_bf, D_INNER, xpw_bf + (size_t)i * 64 * D_INNER, D_INNER,
            nullptr, dbc, 64, D_INNER);

        // fused dt_proj + scan + D skip + silu(z) gate; y -> bf16
        scan_kernel<<<dim3(D_INNER / 16, BATCH), 256, 0, stream>>>(
            dbc, xr_bf, xz,
            dtp_w + (size_t)i * D_INNER * DT_RANK, dtp_b + (size_t)i * D_INNER,
            A_log + (size_t)i * D_INNER * D_STATE, Dp + (size_t)i * D_INNER, y_bf);

        // h = h + y @ out_proj_w[i].T   (4096 x 512, K=1024)  [bf16 MFMA]
        gemm_mfma<128, 64><<<dim3(D_MODEL / 64, NTOK / 128), 256, 0, stream>>>(
            y_bf, D_INNER, outw_bf + (size_t)i * D_MODEL * D_INNER, D_INNER,
            h, h, D_MODEL, D_INNER);
    }

    dec_kernel<<<BATCH, 256, 0, stream>>>(h, dec_w1, dec_b1, dec_w2, dec_b2, out);
}

// Round 9
// 786.062 us; speedup vs baseline: 2.1697x; 1.0291x over previous
//
#include <hip/hip_runtime.h>
#include <math.h>

#define BATCH   8
#define SEQ     512
#define IN_DIM  32
#define D_MODEL 512
#define N_LAYERS 4
#define D_INNER 1024
#define D_STATE 16
#define D_CONV  4
#define DT_RANK 32
#define NTOK    (BATCH * SEQ)   // 4096
#define CHUNK   128             // scan L-chunk staged in LDS

typedef __attribute__((ext_vector_type(8))) short short8_t;
typedef __attribute__((ext_vector_type(4))) float floatx4;

__device__ __forceinline__ float sigmoidf_(float x) { return 1.f / (1.f + __expf(-x)); }

// fp32 -> bf16 round-to-nearest-even (finite inputs)
__device__ __forceinline__ unsigned short f2bf(float f) {
    unsigned int u = __float_as_uint(f);
    return (unsigned short)((u + 0x7fffu + ((u >> 16) & 1u)) >> 16);
}
__device__ __forceinline__ float bf2f(unsigned short u) {
    return __uint_as_float((unsigned int)u << 16);
}

// sum x across each 16-lane row group via DPP (VALU pipe, no LDS traffic)
__device__ __forceinline__ float rowsum16(float x) {
    int t;
    t = __builtin_amdgcn_update_dpp(0, __float_as_int(x), 0xB1, 0xF, 0xF, true);  // quad_perm [1,0,3,2]
    x += __int_as_float(t);
    t = __builtin_amdgcn_update_dpp(0, __float_as_int(x), 0x4E, 0xF, 0xF, true);  // quad_perm [2,3,0,1]
    x += __int_as_float(t);
    t = __builtin_amdgcn_update_dpp(0, __float_as_int(x), 0x124, 0xF, 0xF, true); // row_ror:4
    x += __int_as_float(t);
    t = __builtin_amdgcn_update_dpp(0, __float_as_int(x), 0x128, 0xF, 0xF, true); // row_ror:8
    x += __int_as_float(t);
    return x;
}

// one-shot fp32->bf16 cast of the three MFMA weight tensors (single dispatch)
__global__ __launch_bounds__(256) void cast_all_kernel(
    const float* __restrict__ a, unsigned short* __restrict__ oa, int qa,   // vec4 counts
    const float* __restrict__ b, unsigned short* __restrict__ ob, int qb,
    const float* __restrict__ c, unsigned short* __restrict__ oc, int qc)
{
    int v = blockIdx.x * 256 + threadIdx.x;
    const float* in; unsigned short* out;
    if (v < qa)                { in = a; out = oa; }
    else if (v < qa + qb)      { v -= qa; in = b; out = ob; }
    else if (v < qa + qb + qc) { v -= qa + qb; in = c; out = oc; }
    else return;
    const float4 x = *(const float4*)&in[v * 4];
    ushort4 o;
    o.x = f2bf(x.x); o.y = f2bf(x.y); o.z = f2bf(x.z); o.w = f2bf(x.w);
    *(ushort4*)&out[v * 4] = o;
}

// ---------------- bf16 MFMA GEMM ----------------
// OUTBF=false: C fp32, optional residual R. OUTBF=true: C bf16 (no residual).
template<int BM, int BN, bool OUTBF>
__global__ __launch_bounds__(256) void gemm_mfma(
    const unsigned short* __restrict__ A, int lda,
    const unsigned short* __restrict__ W, int ldw,
    const float* __restrict__ R,
    void* __restrict__ Cv, int ldc,
    int K)
{
    constexpr int MT = BM / 32;
    constexpr int NT = BN / 32;
    constexpr int LDSP = 40;
    __shared__ __align__(16) unsigned short sA[BM * LDSP];
    __shared__ __align__(16) unsigned short sB[BN * LDSP];

    const int tid  = threadIdx.x;
    const int lane = tid & 63;
    const int wave = tid >> 6;
    const int wm0  = (wave >> 1) * (BM / 2);
    const int wn0  = (wave & 1) * (BN / 2);
    const int lrow = lane & 15;
    const int lko  = (lane >> 4) * 8;
    const int m0 = blockIdx.y * BM;
    const int n0 = blockIdx.x * BN;

    floatx4 acc[MT][NT];
    #pragma unroll
    for (int mt = 0; mt < MT; ++mt)
        #pragma unroll
        for (int nt = 0; nt < NT; ++nt)
            acc[mt][nt] = (floatx4){0.f, 0.f, 0.f, 0.f};

    for (int k0 = 0; k0 < K; k0 += 32) {
        #pragma unroll
        for (int it = 0; it < BM * 4 / 256; ++it) {
            const int idx = it * 256 + tid;
            const int r = idx >> 2, c = (idx & 3) * 8;
            *(short8_t*)&sA[r * LDSP + c] = *(const short8_t*)&A[(size_t)(m0 + r) * lda + k0 + c];
        }
        #pragma unroll
        for (int it = 0; it < BN * 4 / 256; ++it) {
            const int idx = it * 256 + tid;
            const int r = idx >> 2, c = (idx & 3) * 8;
            *(short8_t*)&sB[r * LDSP + c] = *(const short8_t*)&W[(size_t)(n0 + r) * ldw + k0 + c];
        }
        __syncthreads();
        short8_t af[MT], bfr[NT];
        #pragma unroll
        for (int mt = 0; mt < MT; ++mt)
            af[mt] = *(const short8_t*)&sA[(wm0 + mt * 16 + lrow) * LDSP + lko];
        #pragma unroll
        for (int nt = 0; nt < NT; ++nt)
            bfr[nt] = *(const short8_t*)&sB[(wn0 + nt * 16 + lrow) * LDSP + lko];
        #pragma unroll
        for (int mt = 0; mt < MT; ++mt)
            #pragma unroll
            for (int nt = 0; nt < NT; ++nt)
                acc[mt][nt] = __builtin_amdgcn_mfma_f32_16x16x32_bf16(af[mt], bfr[nt], acc[mt][nt], 0, 0, 0);
        __syncthreads();
    }

    #pragma unroll
    for (int mt = 0; mt < MT; ++mt) {
        const int mbase = m0 + wm0 + mt * 16 + (lane >> 4) * 4;
        #pragma unroll
        for (int nt = 0; nt < NT; ++nt) {
            const int n = n0 + wn0 + nt * 16 + (lane & 15);
            #pragma unroll
            for (int r = 0; r < 4; ++r) {
                float v = acc[mt][nt][r];
                if (OUTBF) {
                    ((unsigned short*)Cv)[(size_t)(mbase + r) * ldc + n] = f2bf(v);
                } else {
                    if (R) v += R[(size_t)(mbase + r) * ldc + n];
                    ((float*)Cv)[(size_t)(mbase + r) * ldc + n] = v;
                }
            }
        }
    }
}

// ---------------- fp32 vector GEMM (encoder only) ----------------
__global__ __launch_bounds__(256) void gemm_bt64(
    const float* __restrict__ A, int lda,
    const float* __restrict__ W,
    const float* __restrict__ bias,
    float* __restrict__ C,
    int N, int K, int ldc)
{
    __shared__ __align__(16) float As[16][64];
    __shared__ __align__(16) float Ws[16][64];
    const int tid = threadIdx.x;
    const int tx = tid & 15, ty = tid >> 4;
    const int m0 = blockIdx.y * 64, n0 = blockIdx.x * 64;
    const int lm = tid >> 2;
    const int lk = (tid & 3) * 4;

    float acc[4][4] = {};
    for (int k0 = 0; k0 < K; k0 += 16) {
        float4 av = *(const float4*)&A[(size_t)(m0 + lm) * lda + k0 + lk];
        float4 wv = *(const float4*)&W[(size_t)(n0 + lm) * K   + k0 + lk];
        As[lk + 0][lm] = av.x; As[lk + 1][lm] = av.y; As[lk + 2][lm] = av.z; As[lk + 3][lm] = av.w;
        Ws[lk + 0][lm] = wv.x; Ws[lk + 1][lm] = wv.y; Ws[lk + 2][lm] = wv.z; Ws[lk + 3][lm] = wv.w;
        __syncthreads();
        #pragma unroll
        for (int k = 0; k < 16; ++k) {
            float4 a4 = *(const float4*)&As[k][ty * 4];
            float4 b4 = *(const float4*)&Ws[k][tx * 4];
            float a[4] = {a4.x, a4.y, a4.z, a4.w};
            float b[4] = {b4.x, b4.y, b4.z, b4.w};
            #pragma unroll
            for (int i = 0; i < 4; ++i)
                #pragma unroll
                for (int j = 0; j < 4; ++j)
                    acc[i][j] = fmaf(a[i], b[j], acc[i][j]);
        }
        __syncthreads();
    }
    #pragma unroll
    for (int i = 0; i < 4; ++i) {
        const int m = m0 + ty * 4 + i;
        #pragma unroll
        for (int j = 0; j < 4; ++j) {
            const int n = n0 + tx * 4 + j;
            C[(size_t)m * ldc + n] = acc[i][j] + bias[n];
        }
    }
}

// xn_bf[tok,:] = bf16( h[tok,:] * rsqrt(mean(h^2)+1e-5) * w )
__global__ __launch_bounds__(256) void rmsnorm_kernel(
    const float* __restrict__ h, const float* __restrict__ w, unsigned short* __restrict__ xn)
{
    const int tok = blockIdx.x, tid = threadIdx.x;
    const float* row = h + (size_t)tok * D_MODEL;
    float v0 = row[tid], v1 = row[tid + 256];
    float s = v0 * v0 + v1 * v1;
    #pragma unroll
    for (int off = 32; off > 0; off >>= 1) s += __shfl_down(s, off, 64);
    __shared__ float ss[4];
    if ((tid & 63) == 0) ss[tid >> 6] = s;
    __syncthreads();
    const float total = ss[0] + ss[1] + ss[2] + ss[3];
    const float scale = rsqrtf(total * (1.f / (float)D_MODEL) + 1e-5f);
    unsigned short* orow = xn + (size_t)tok * D_MODEL;
    orow[tid]       = f2bf(v0 * scale * w[tid]);
    orow[tid + 256] = f2bf(v1 * scale * w[tid + 256]);
}

// causal dwconv + silu over bf16 xz x-half -> xr_bf (bf16). Fully coalesced.
__global__ __launch_bounds__(256) void conv_silu_kernel(
    const unsigned short* __restrict__ xz, const float* __restrict__ cw,
    const float* __restrict__ cb, unsigned short* __restrict__ xr_bf)
{
    const int idx = blockIdx.x * 256 + threadIdx.x;   // over NTOK*D_INNER
    const int d   = idx & (D_INNER - 1);
    const int tok = idx >> 10;
    const int l   = tok & (SEQ - 1);
    float acc = cb[d];
    #pragma unroll
    for (int k = 0; k < D_CONV; ++k) {
        const int t = l - (D_CONV - 1) + k;
        if (t >= 0)
            acc = fmaf(bf2f(xz[(size_t)(tok + t - l) * (2 * D_INNER) + d]), cw[d * D_CONV + k], acc);
    }
    const float v = acc * sigmoidf_(acc);
    xr_bf[(size_t)tok * D_INNER + d] = f2bf(v);
}

// ---------------- fused dt_proj + selective scan + gate ----------------
// Thread = (d, n). Register-prefetch double-buffer: chunk k+1's dbc/x/z loaded
// into VGPRs during chunk k's compute; LDS-written at the next iteration's top.
// Conflict hygiene: delta-dot lanes read CONSECUTIVE l (l = 16*ls+lg) ->
// conflict-free b128 sDT reads; sDX padded to 17 float2/row (stride 34 words).
__global__ __launch_bounds__(256) void scan_kernel(
    const float* __restrict__ dbc,   const unsigned short* __restrict__ xrbf,
    const unsigned short* __restrict__ xzbf, const float* __restrict__ dtp_w,
    const float* __restrict__ dtp_b, const float* __restrict__ A_log,
    const float* __restrict__ Dp,    unsigned short* __restrict__ y)
{
    __shared__ __align__(16) float  sDT[CHUNK][36];    // dt rows (32 used)
    __shared__ __align__(16) float2 sBC[CHUNK * 16];   // (B_n, C_n)
    __shared__ __align__(16) float2 sDX[CHUNK * 17];   // (.x=delta, .y=x), padded row
    __shared__ __align__(16) float  sY [CHUNK * 16];
    const int b   = blockIdx.y;
    const int tid = threadIdx.x;
    const int n   = tid & 15;
    const int dl  = tid >> 4;
    const int d0  = blockIdx.x * 16;
    const int dl_c = tid & 15;      // delta-phase channel
    const int lg   = tid >> 4;      // delta-phase l-group (0..15)
    const int prow = tid >> 1, phalf = tid & 1;   // x-staging mapping

    // per-thread dt_proj weight row
    float4 wv[8];
    {
        const float* wr = dtp_w + (size_t)(d0 + dl_c) * DT_RANK;
        #pragma unroll
        for (int q = 0; q < 8; ++q) wv[q] = *(const float4*)&wr[q * 4];
    }
    const float dtb = dtp_b[d0 + dl_c];
    const float An = -__expf(A_log[(size_t)(d0 + dl) * D_STATE + n]);
    const float Dd = Dp[d0 + dl];

    // prefetch registers
    float4   pdv[8];
    short8_t pxv;
    ushort4  pzv[2];

    #define LOAD_CHUNK(L0)                                                                 \
    {                                                                                      \
        _Pragma("unroll")                                                                  \
        for (int it = 0; it < 8; ++it) {                                                   \
            const int idx = it * 256 + tid;                                                \
            pdv[it] = *(const float4*)&dbc[((size_t)(b * SEQ + (L0) + (idx >> 4))) * 64 + (idx & 15) * 4]; \
        }                                                                                  \
        pxv = *(const short8_t*)&xrbf[((size_t)(b * SEQ + (L0) + prow)) * D_INNER + d0 + phalf * 8];      \
        _Pragma("unroll")                                                                  \
        for (int it = 0; it < 2; ++it) {                                                   \
            const int idx = it * 256 + tid;                                                \
            pzv[it] = *(const ushort4*)&xzbf[((size_t)(b * SEQ + (L0) + (idx >> 2))) * (2 * D_INNER) + D_INNER + d0 + (idx & 3) * 4]; \
        }                                                                                  \
    }

    LOAD_CHUNK(0);
    float h = 0.f;
    for (int l0 = 0; l0 < SEQ; l0 += CHUNK) {
        // ---- write prefetched regs to LDS ----
        #pragma unroll
        for (int it = 0; it < 8; ++it) {
            const int idx = it * 256 + tid;
            const int row = idx >> 4, q = idx & 15;
            const float4 v = pdv[it];
            if (q < 8) {
                *(float4*)&sDT[row][q * 4] = v;
            } else if (q < 12) {
                const int c = (q - 8) * 4;
                float* base = (float*)&sBC[row * 16];
                base[2*(c+0)] = v.x; base[2*(c+1)] = v.y; base[2*(c+2)] = v.z; base[2*(c+3)] = v.w;
            } else {
                const int c = (q - 12) * 4;
                float* base = (float*)&sBC[row * 16];
                base[2*(c+0)+1] = v.x; base[2*(c+1)+1] = v.y; base[2*(c+2)+1] = v.z; base[2*(c+3)+1] = v.w;
            }
        }
        #pragma unroll
        for (int j = 0; j < 8; ++j)
            sDX[prow * 17 + phalf * 8 + j].y = bf2f((unsigned short)pxv[j]);
        const ushort4 zc0 = pzv[0], zc1 = pzv[1];   // capture z of current chunk
        __syncthreads();

        // issue next chunk's global loads early (consumed after next barrier set)
        if (l0 + CHUNK < SEQ) LOAD_CHUNK(l0 + CHUNK);

        // ---- delta = softplus(dt @ W + b): lanes read consecutive l ----
        #pragma unroll
        for (int ls = 0; ls < 8; ++ls) {
            const int l = ls * 16 + lg;
            float a = dtb;
            #pragma unroll
            for (int q = 0; q < 8; ++q) {
                const float4 t4 = *(const float4*)&sDT[l][q * 4];
                a = fmaf(t4.x, wv[q].x, a); a = fmaf(t4.y, wv[q].y, a);
                a = fmaf(t4.z, wv[q].z, a); a = fmaf(t4.w, wv[q].w, a);
            }
            const float dlt = (a > 20.f) ? a : log1pf(__expf(a));
            sDX[l * 17 + dl_c].x = dlt;
        }
        __syncthreads();

        // ---- recurrence ----
        #pragma unroll 4
        for (int l = 0; l < CHUNK; ++l) {
            const float2 dx = sDX[l * 17 + dl];
            const float2 bc = sBC[l * 16 + n];
            const float e = __expf(dx.x * An);
            h = fmaf(e, h, dx.x * dx.y * bc.x);
            const float p = rowsum16(h * bc.y);
            if (n == 0) sY[l * 16 + dl] = fmaf(Dd, dx.y, p);
        }
        __syncthreads();

        // ---- store: y = sY * silu(z) (z bf16, prefetched) ----
        #pragma unroll
        for (int it = 0; it < 2; ++it) {
            const int idx = it * 256 + tid;
            const int l = idx >> 2, q = idx & 3;
            const size_t row = (size_t)(b * SEQ + l0 + l);
            const ushort4 zu = (it == 0) ? zc0 : zc1;
            const float z0 = bf2f(zu.x), z1 = bf2f(zu.y), z2 = bf2f(zu.z), z3 = bf2f(zu.w);
            const float4 yv = *(const float4*)&sY[l * 16 + q * 4];
            ushort4 o;
            o.x = f2bf(yv.x * z0 * sigmoidf_(z0));
            o.y = f2bf(yv.y * z1 * sigmoidf_(z1));
            o.z = f2bf(yv.z * z2 * sigmoidf_(z2));
            o.w = f2bf(yv.w * z3 * sigmoidf_(z3));
            *(ushort4*)&y[row * D_INNER + d0 + q * 4] = o;
        }
        // store(k) reads sY only; next iteration's LDS-writes touch sDT/sBC/sDX
        // (disjoint) and are ordered by the __syncthreads() after them.
    }
    #undef LOAD_CHUNK
}

// fused decoder: out[b] = relu(h_last @ w1.T + b1) @ w2 + b2; one block per batch
__global__ __launch_bounds__(256) void dec_kernel(
    const float* __restrict__ h, const float* __restrict__ w1, const float* __restrict__ b1,
    const float* __restrict__ w2, const float* __restrict__ b2, float* __restrict__ out)
{
    __shared__ __align__(16) float hr[D_MODEL];
    __shared__ float part[4];
    const int b = blockIdx.x, j = threadIdx.x;
    const float* row = h + ((size_t)(b * SEQ + SEQ - 1)) * D_MODEL;
    hr[j] = row[j];
    hr[j + 256] = row[j + 256];
    __syncthreads();
    float acc = b1[j];
    const float* wr = w1 + (size_t)j * D_MODEL;
    for (int k = 0; k < D_MODEL; k += 4) {
        const float4 wvv = *(const float4*)&wr[k];
        const float4 hv = *(const float4*)&hr[k];
        acc = fmaf(wvv.x, hv.x, acc); acc = fmaf(wvv.y, hv.y, acc);
        acc = fmaf(wvv.z, hv.z, acc); acc = fmaf(wvv.w, hv.w, acc);
    }
    float s = fmaxf(acc, 0.f) * w2[j];
    #pragma unroll
    for (int off = 32; off > 0; off >>= 1) s += __shfl_down(s, off, 64);
    if ((j & 63) == 0) part[j >> 6] = s;
    __syncthreads();
    if (j == 0) out[b] = part[0] + part[1] + part[2] + part[3] + b2[0];
}

extern "C" void kernel_launch(void* const* d_in, const int* in_sizes, int n_in,
                              void* d_out, int out_size, void* d_ws, size_t ws_size,
                              hipStream_t stream)
{
    const float* x      = (const float*)d_in[0];
    const float* enc_w  = (const float*)d_in[1];
    const float* enc_b  = (const float*)d_in[2];
    const float* in_w   = (const float*)d_in[3];
    const float* conv_w = (const float*)d_in[4];
    const float* conv_b = (const float*)d_in[5];
    const float* xp_w   = (const float*)d_in[6];
    const float* dtp_w  = (const float*)d_in[7];
    const float* dtp_b  = (const float*)d_in[8];
    const float* A_log  = (const float*)d_in[9];
    const float* Dp     = (const float*)d_in[10];
    const float* out_w  = (const float*)d_in[11];
    const float* norm_w = (const float*)d_in[12];
    const float* dec_w1 = (const float*)d_in[13];
    const float* dec_b1 = (const float*)d_in[14];
    const float* dec_w2 = (const float*)d_in[15];
    const float* dec_b2 = (const float*)d_in[16];
    float* out = (float*)d_out;

    // workspace layout
    float* ws    = (float*)d_ws;
    float* h     = ws;                                   // NTOK*512 fp32
    float* dbc   = h + (size_t)NTOK * D_MODEL;           // NTOK*64 fp32
    float* d1pad = dbc + (size_t)NTOK * 64;              // (align pad not needed; reuse)
    unsigned short* xz_bf   = (unsigned short*)(d1pad);                              // NTOK*2048
    unsigned short* xn_bf   = xz_bf   + (size_t)NTOK * 2 * D_INNER;                  // NTOK*512
    unsigned short* y_bf    = xn_bf   + (size_t)NTOK * D_MODEL;                      // NTOK*1024
    unsigned short* xr_bf   = y_bf    + (size_t)NTOK * D_INNER;                      // NTOK*1024
    unsigned short* inw_bf  = xr_bf   + (size_t)NTOK * D_INNER;                      // 4*2048*512
    unsigned short* outw_bf = inw_bf  + (size_t)N_LAYERS * 2 * D_INNER * D_MODEL;    // 4*512*1024
    unsigned short* xpw_bf  = outw_bf + (size_t)N_LAYERS * D_MODEL * D_INNER;        // 4*64*1024

    const int qa = N_LAYERS * 2 * D_INNER * D_MODEL / 4;   // in_proj  vec4 count
    const int qb = N_LAYERS * D_MODEL * D_INNER / 4;       // out_proj
    const int qc = N_LAYERS * 64 * D_INNER / 4;            // x_proj
    cast_all_kernel<<<(qa + qb + qc + 255) / 256, 256, 0, stream>>>(
        in_w, inw_bf, qa, out_w, outw_bf, qb, xp_w, xpw_bf, qc);

    // encoder: h = x @ enc_w.T + enc_b   (fp32, K=32)
    gemm_bt64<<<dim3(D_MODEL / 64, NTOK / 64), 256, 0, stream>>>(
        x, IN_DIM, enc_w, enc_b, h, D_MODEL, IN_DIM, D_MODEL);

    for (int i = 0; i < N_LAYERS; ++i) {
        rmsnorm_kernel<<<NTOK, 256, 0, stream>>>(h, norm_w + (size_t)i * D_MODEL, xn_bf);

        // xz = xn @ in_proj_w[i].T  (4096 x 2048, K=512) [bf16 MFMA, bf16 out]
        gemm_mfma<128, 128, true><<<dim3(2 * D_INNER / 128, NTOK / 128), 256, 0, stream>>>(
            xn_bf, D_MODEL, inw_bf + (size_t)i * 2 * D_INNER * D_MODEL, D_MODEL,
            nullptr, xz_bf, 2 * D_INNER, D_MODEL);

        // xr_bf = bf16(silu(causal_dwconv(xz x-half) + cb))
        conv_silu_kernel<<<NTOK * D_INNER / 256, 256, 0, stream>>>(
            xz_bf, conv_w + (size_t)i * D_INNER * D_CONV, conv_b + (size_t)i * D_INNER, xr_bf);

        // dbc = xr @ x_proj_w[i].T  (4096 x 64, K=1024) [bf16 MFMA, fp32 out]
        gemm_mfma<64, 64, false><<<dim3(1, NTOK / 64), 256, 0, stream>>>(
            xr_bf, D_INNER, xpw_bf + (size_t)i * 64 * D_INNER, D_INNER,
            nullptr, dbc, 64, D_INNER);

        // fused dt_proj + scan + D skip + silu(z) gate; y -> bf16
        scan_kernel<<<dim3(D_INNER / 16, BATCH), 256, 0, stream>>>(
            dbc, xr_bf, xz_bf,
            dtp_w + (size_t)i * D_INNER * DT_RANK, dtp_b + (size_t)i * D_INNER,
            A_log + (size_t)i * D_INNER * D_STATE, Dp + (size_t)i * D_INNER, y_bf);

        // h = h + y @ out_proj_w[i].T  (4096 x 512, K=1024) [bf16 MFMA, fp32 out + residual]
        gemm_mfma<128, 64, false><<<dim3(D_MODEL / 64, NTOK / 128), 256, 0, stream>>>(
            y_bf, D_INNER, outw_bf + (size_t)i * D_MODEL * D_INNER, D_INNER,
            h, h, D_MODEL, D_INNER);
    }

    dec_kernel<<<BATCH, 256, 0, stream>>>(h, dec_w1, dec_b1, dec_w2, dec_b2, out);
}